// Round 12
// baseline (216.194 us; speedup 1.0000x reference)
//
#include <hip/hip_runtime.h>
#include <hip/hip_bf16.h>
#include <math.h>

typedef __bf16 bf16x8 __attribute__((ext_vector_type(8)));
typedef __bf16 bf16x4 __attribute__((ext_vector_type(4)));
typedef float f32x4 __attribute__((ext_vector_type(4)));

#define N_TOK 4096
#define EDIM 512
#define NHEAD 8
#define HD 64
#define LDCOMB 896
#define NBIN 100
#define SPLITK 8
#define BK 64

// prep block partition (cvt now folded into gemm2)
#define NU_TC 64
#define NU_ADD 128
#define NU_TMAT 128
#define NB_PREP (NU_TC + NU_ADD + NU_TMAT + 1)

__device__ __forceinline__ bf16x8 cvt8(const float* p) {
    const float4 a = *(const float4*)p;
    const float4 b = *(const float4*)(p + 4);
    bf16x8 o;
    o[0] = (__bf16)a.x; o[1] = (__bf16)a.y; o[2] = (__bf16)a.z; o[3] = (__bf16)a.w;
    o[4] = (__bf16)b.x; o[5] = (__bf16)b.y; o[6] = (__bf16)b.z; o[7] = (__bf16)b.w;
    return o;
}

// ---------------- prep: w_out^T + add2 + time-matrix + sort/plan ----------------
__global__ __launch_bounds__(256) void prep_kernel(
    const float* __restrict__ w_mlp, const float* __restrict__ w_out,
    const float* __restrict__ status, const float* __restrict__ out_b,
    const float* __restrict__ mlp_b, const int* __restrict__ steps,
    __bf16* __restrict__ woutT_bf,
    float* __restrict__ add2, __bf16* __restrict__ tmat,
    int* __restrict__ perm, int* __restrict__ sstep,
    int* __restrict__ bs_row, int* __restrict__ qinfo) {
    __shared__ float T[64][65];
    __shared__ int hist[NBIN];
    __shared__ int offs[NBIN];
    const int bid = blockIdx.x;
    const int tid = threadIdx.x;
    const int wave = tid >> 6, lane = tid & 63;

    if (bid < NU_TC) {
        // transpose+cvt w_out -> woutT[k][m]
        const int m0 = (bid >> 3) * 64, k0 = (bid & 7) * 64;
        const int row = tid >> 2, c4 = (tid & 3) * 16;
        #pragma unroll
        for (int i = 0; i < 4; i++) {
            const float4 v = *(const float4*)&w_out[(size_t)(m0 + row) * EDIM + k0 + c4 + i * 4];
            T[row][c4 + i * 4 + 0] = v.x;
            T[row][c4 + i * 4 + 1] = v.y;
            T[row][c4 + i * 4 + 2] = v.z;
            T[row][c4 + i * 4 + 3] = v.w;
        }
        __syncthreads();
        const int kr = tid >> 2, m16 = (tid & 3) * 16;
        bf16x8 o0, o1;
        #pragma unroll
        for (int i = 0; i < 8; i++) o0[i] = (__bf16)T[m16 + i][kr];
        #pragma unroll
        for (int i = 0; i < 8; i++) o1[i] = (__bf16)T[m16 + 8 + i][kr];
        *(bf16x8*)&woutT_bf[(size_t)(k0 + kr) * EDIM + m0 + m16] = o0;
        *(bf16x8*)&woutT_bf[(size_t)(k0 + kr) * EDIM + m0 + m16 + 8] = o1;
    } else if (bid < NU_TC + NU_ADD) {
        // add2[m][j] = status[m].w_mlp[j,512:640] + mlp_b[j] + w_mlp[j,:512].b_out
        const int j = (bid - NU_TC) * 4 + wave;
        const float* wr = w_mlp + (size_t)j * LDCOMB;
        const int k8 = lane * 8;
        const float4 wa = *(const float4*)&wr[k8], wb = *(const float4*)&wr[k8 + 4];
        const float4 oa = *(const float4*)&out_b[k8], ob = *(const float4*)&out_b[k8 + 4];
        float b = wa.x * oa.x + wa.y * oa.y + wa.z * oa.z + wa.w * oa.w +
                  wb.x * ob.x + wb.y * ob.y + wb.z * ob.z + wb.w * ob.w;
        const int c2 = lane * 2;
        const float w0 = wr[EDIM + c2], w1 = wr[EDIM + c2 + 1];
        float s0 = status[c2] * w0 + status[c2 + 1] * w1;
        float s1 = status[128 + c2] * w0 + status[129 + c2] * w1;
        #pragma unroll
        for (int m = 1; m < 64; m <<= 1) {
            b += __shfl_xor(b, m);
            s0 += __shfl_xor(s0, m);
            s1 += __shfl_xor(s1, m);
        }
        if (lane == 0) {
            const float bb = b + mlp_b[j];
            add2[j] = s0 + bb;
            add2[EDIM + j] = s1 + bb;
        }
    } else if (bid < NU_TC + NU_ADD + NU_TMAT) {
        // bf16 time matrix [128][256] (rows >= 100 are padding, masked at tv store)
        const int st = bid - NU_TC - NU_ADD;
        const int c = tid;
        const int pp = c >> 1;
        const float div = expf((float)(2 * pp) * (-9.210340371976184f / 256.0f));
        const float ang = (float)st * div;
        tmat[st * 256 + c] = (__bf16)((c & 1) ? cosf(ang) : sinf(ang));
    } else {
        // counting sort by step + bs_row + per-qtile plan
        if (tid < NBIN) hist[tid] = 0;
        __syncthreads();
        for (int i = tid; i < N_TOK; i += 256)
            atomicAdd(&hist[min(max(steps[i], 0), NBIN - 1)], 1);
        __syncthreads();
        if (tid == 0) {
            int acc = 0;
            for (int s = 0; s < NBIN; s++) { offs[s] = acc; acc += hist[s]; }
        }
        __syncthreads();
        if (tid < NBIN) hist[tid] = offs[tid];   // immutable copy of bin_start
        __syncthreads();
        for (int i = tid; i < N_TOK; i += 256) {
            const int s = min(max(steps[i], 0), NBIN - 1);
            const int pos = atomicAdd(&offs[s], 1);
            perm[pos] = i;
            sstep[pos] = s;
        }
        __syncthreads();
        for (int q = tid; q < N_TOK; q += 256)
            bs_row[q] = hist[sstep[q]];
        __syncthreads();
        for (int qt = tid; qt < 64; qt += 256) {
            qinfo[qt * 2] = bs_row[qt * 64] & ~(BK - 1);
            qinfo[qt * 2 + 1] = bs_row[qt * 64 + 63];
        }
    }
}

// ---------------- merged GEMMs with in-staging fp32->bf16 cvt ----------------
// qkv->sorted qs/ks/vt (384) + weff (16) + tv (4)
__global__ __launch_bounds__(256) void gemm2_kernel(const float* __restrict__ x,
                                                    const float* __restrict__ w_in,
                                                    const float* __restrict__ b_in,
                                                    const int* __restrict__ perm,
                                                    __bf16* __restrict__ qs,
                                                    __bf16* __restrict__ ks,
                                                    __bf16* __restrict__ vt,
                                                    const float* __restrict__ w_mlp,
                                                    const __bf16* __restrict__ woutT_bf,
                                                    __bf16* __restrict__ weff_bf,
                                                    const __bf16* __restrict__ tmat,
                                                    float* __restrict__ tv) {
    __shared__ __attribute__((aligned(16))) union {
        struct { __bf16 As[128][40]; __bf16 Bs[128][40]; } g;
        __bf16 T[128][72];
    } sm;
    __shared__ int pr[128];
    const int bid = blockIdx.x;
    const int tid = threadIdx.x;
    const int wave = tid >> 6, lane = tid & 63;
    const int wm = (wave >> 1) * 64, wn = (wave & 1) * 64;
    const int lr = lane & 15, lq = lane >> 4;

    // mode 0: A = x (fp32, perm-gathered), B = w_in (fp32)
    // mode 1: A = w_mlp[:, :512] (fp32, ld 896), B = woutT (bf16)
    // mode 2: A = tmat (bf16), B = w_mlp+640 (fp32, ld 896)
    const float *Af = nullptr, *Bf = nullptr;
    const __bf16 *Ab = nullptr, *Bb = nullptr;
    int lda, ldb, bm, bn, K, mode;
    if (bid < 384) {
        Af = x; lda = EDIM; Bf = w_in; ldb = EDIM; K = EDIM; mode = 0;
        bm = (bid & 31) * 128; bn = (bid >> 5) * 128;
        if (tid < 128) pr[tid] = perm[bm + tid];
    } else if (bid < 400) {
        const int b2 = bid - 384;
        Af = w_mlp; lda = LDCOMB; Bb = woutT_bf; ldb = EDIM; K = EDIM; mode = 1;
        bm = (b2 & 3) * 128; bn = (b2 >> 2) * 128;
    } else {
        const int b3 = bid - 400;
        Ab = tmat; lda = 256; Bf = w_mlp + 640; ldb = LDCOMB; K = 256; mode = 2;
        bm = 0; bn = b3 * 128;
    }

    f32x4 acc[4][4] = {};
    for (int k0 = 0; k0 < K; k0 += 32) {
        __syncthreads();
        #pragma unroll
        for (int c = tid; c < 512; c += 256) {
            const int row = c >> 2, k8 = (c & 3) * 8;
            const int arow = (mode == 0) ? pr[row] : (bm + row);
            bf16x8 av, bv;
            if (Af) av = cvt8(&Af[(size_t)arow * lda + k0 + k8]);
            else    av = *(const bf16x8*)&Ab[(size_t)arow * lda + k0 + k8];
            if (Bf) bv = cvt8(&Bf[(size_t)(bn + row) * ldb + k0 + k8]);
            else    bv = *(const bf16x8*)&Bb[(size_t)(bn + row) * ldb + k0 + k8];
            *(bf16x8*)&sm.g.As[row][k8] = av;
            *(bf16x8*)&sm.g.Bs[row][k8] = bv;
        }
        __syncthreads();
        bf16x8 af[4], bfr[4];
        #pragma unroll
        for (int i = 0; i < 4; i++) {
            af[i]  = *(const bf16x8*)&sm.g.As[wm + i * 16 + lr][lq * 8];
            bfr[i] = *(const bf16x8*)&sm.g.Bs[wn + i * 16 + lr][lq * 8];
        }
        #pragma unroll
        for (int i = 0; i < 4; i++)
            #pragma unroll
            for (int j = 0; j < 4; j++)
                acc[i][j] = __builtin_amdgcn_mfma_f32_16x16x32_bf16(af[i], bfr[j], acc[i][j], 0, 0, 0);
    }

    if (mode == 1) {
        #pragma unroll
        for (int i = 0; i < 4; i++)
            #pragma unroll
            for (int j = 0; j < 4; j++) {
                const int col = bn + wn + j * 16 + lr;
                #pragma unroll
                for (int r = 0; r < 4; r++)
                    weff_bf[(size_t)(bm + wm + i * 16 + lq * 4 + r) * EDIM + col] =
                        (__bf16)acc[i][j][r];
            }
    } else if (mode == 2) {
        #pragma unroll
        for (int i = 0; i < 4; i++)
            #pragma unroll
            for (int j = 0; j < 4; j++) {
                const int col = bn + wn + j * 16 + lr;
                #pragma unroll
                for (int r = 0; r < 4; r++) {
                    const int row = wm + i * 16 + lq * 4 + r;
                    if (row < NBIN) tv[(size_t)row * EDIM + col] = acc[i][j][r];
                }
            }
    } else if (bn < 512) {
        // Q: pre-scale by 1/8*log2(e), sorted rows
        const float SC = 0.125f * 1.44269504f;
        #pragma unroll
        for (int i = 0; i < 4; i++)
            #pragma unroll
            for (int j = 0; j < 4; j++) {
                const int col = bn + wn + j * 16 + lr;
                const float bv = b_in[col];
                #pragma unroll
                for (int r = 0; r < 4; r++)
                    qs[(size_t)(bm + wm + i * 16 + lq * 4 + r) * EDIM + col] =
                        (__bf16)((acc[i][j][r] + bv) * SC);
            }
    } else if (bn < 1024) {
        // K: sorted rows
        #pragma unroll
        for (int i = 0; i < 4; i++)
            #pragma unroll
            for (int j = 0; j < 4; j++) {
                const int col = bn + wn + j * 16 + lr;
                const float bv = b_in[col];
                #pragma unroll
                for (int r = 0; r < 4; r++)
                    ks[(size_t)(bm + wm + i * 16 + lq * 4 + r) * EDIM + (col - 512)] =
                        (__bf16)(acc[i][j][r] + bv);
            }
    } else {
        // V: transpose 128x128 tile via LDS, two 64-col halves -> vt[dim][token]
        #pragma unroll
        for (int half = 0; half < 2; half++) {
            __syncthreads();
            if ((wave & 1) == half) {
                #pragma unroll
                for (int i = 0; i < 4; i++)
                    #pragma unroll
                    for (int j = 0; j < 4; j++) {
                        const float bv = b_in[bn + wn + j * 16 + lr];
                        #pragma unroll
                        for (int r = 0; r < 4; r++)
                            sm.T[wm + i * 16 + lq * 4 + r][j * 16 + lr] =
                                (__bf16)(acc[i][j][r] + bv);
                    }
            }
            __syncthreads();
            for (int u = tid; u < 1024; u += 256) {
                const int d = u & 63, t8 = (u >> 6) * 8;
                bf16x8 v;
                #pragma unroll
                for (int j = 0; j < 8; j++) v[j] = sm.T[t8 + j][d];
                const int dim = (bn - 1024) + half * 64 + d;
                *(bf16x8*)&vt[(size_t)dim * N_TOK + bm + t8] = v;
            }
        }
    }
}

// ---------------- flash attention: BQ=64 (R6 config), split-K grid ----------------
__global__ __launch_bounds__(256) void attn_kernel(const __bf16* __restrict__ qs,
                                                   const __bf16* __restrict__ ks,
                                                   const __bf16* __restrict__ vt,
                                                   const int* __restrict__ bs_row,
                                                   const int* __restrict__ qinfo,
                                                   __bf16* __restrict__ po,
                                                   float* __restrict__ pl) {
    __shared__ __attribute__((aligned(16))) __bf16 Ks[BK][72];     // [key][d]
    __shared__ __attribute__((aligned(16))) __bf16 Vs[64][BK + 8]; // [d][key]
    __shared__ __attribute__((aligned(16))) __bf16 Ps[64][BK + 8]; // [q][key] wave bands

    const int h = blockIdx.y;
    const int qtile = blockIdx.x;
    const int ck = blockIdx.z;
    const int tid = threadIdx.x, wave = tid >> 6, lane = tid & 63;
    const int lr = lane & 15, lq = lane >> 4;
    const int qbase = qtile * 64 + wave * 16;

    const int kt0 = qinfo[qtile * 2];
    const int bs_blockmax = qinfo[qtile * 2 + 1];
    const int nt = (N_TOK - kt0) / BK;
    const int kta = kt0 + ((nt * ck) / SPLITK) * BK;
    const int ktb = kt0 + ((nt * (ck + 1)) / SPLITK) * BK;

    bf16x8 aq[2];
    {
        const __bf16* qrow = qs + (size_t)(qbase + lr) * EDIM + h * HD;
        aq[0] = *(const bf16x8*)&qrow[lq * 8];
        aq[1] = *(const bf16x8*)&qrow[32 + lq * 8];
    }
    int bs_r[4];
    #pragma unroll
    for (int r = 0; r < 4; r++) bs_r[r] = bs_row[qbase + lq * 4 + r];

    float l_i[4] = {0.f, 0.f, 0.f, 0.f};
    f32x4 o[4] = {};

    const __bf16* kbase = ks + h * HD;
    const __bf16* vbase = vt + (size_t)h * HD * N_TOK;

    const int r0 = tid >> 3, r1 = r0 + 32, k8 = (tid & 7) * 8;
    bf16x8 kr0, kr1, vr0, vr1;
    if (kta < ktb) {
        kr0 = *(const bf16x8*)&kbase[(size_t)(kta + r0) * EDIM + k8];
        kr1 = *(const bf16x8*)&kbase[(size_t)(kta + r1) * EDIM + k8];
        vr0 = *(const bf16x8*)&vbase[(size_t)r0 * N_TOK + kta + k8];
        vr1 = *(const bf16x8*)&vbase[(size_t)r1 * N_TOK + kta + k8];
    }

    for (int kt = kta; kt < ktb; kt += BK) {
        __syncthreads();
        *(bf16x8*)&Ks[r0][k8] = kr0;
        *(bf16x8*)&Ks[r1][k8] = kr1;
        *(bf16x8*)&Vs[r0][k8] = vr0;
        *(bf16x8*)&Vs[r1][k8] = vr1;
        __syncthreads();
        if (kt + BK < ktb) {
            kr0 = *(const bf16x8*)&kbase[(size_t)(kt + BK + r0) * EDIM + k8];
            kr1 = *(const bf16x8*)&kbase[(size_t)(kt + BK + r1) * EDIM + k8];
            vr0 = *(const bf16x8*)&vbase[(size_t)r0 * N_TOK + kt + BK + k8];
            vr1 = *(const bf16x8*)&vbase[(size_t)r1 * N_TOK + kt + BK + k8];
        }

        f32x4 s[4];
        #pragma unroll
        for (int t = 0; t < 4; t++) {
            bf16x8 b0 = *(const bf16x8*)&Ks[t * 16 + lr][lq * 8];
            bf16x8 b1 = *(const bf16x8*)&Ks[t * 16 + lr][32 + lq * 8];
            f32x4 a = {};
            a = __builtin_amdgcn_mfma_f32_16x16x32_bf16(aq[0], b0, a, 0, 0, 0);
            a = __builtin_amdgcn_mfma_f32_16x16x32_bf16(aq[1], b1, a, 0, 0, 0);
            s[t] = a;
        }
        if (kt < bs_blockmax) {
            #pragma unroll
            for (int t = 0; t < 4; t++) {
                const int col = kt + t * 16 + lr;
                #pragma unroll
                for (int r = 0; r < 4; r++)
                    if (col < bs_r[r]) s[t][r] = -1e9f;
            }
        }
        #pragma unroll
        for (int t = 0; t < 4; t++) {
            #pragma unroll
            for (int r = 0; r < 4; r++) {
                const float pr = exp2f(s[t][r]);
                l_i[r] += pr;
                Ps[wave * 16 + lq * 4 + r][t * 16 + lr] = (__bf16)pr;
            }
        }
        #pragma unroll
        for (int ks2 = 0; ks2 < 2; ks2++) {
            bf16x8 ap = *(const bf16x8*)&Ps[wave * 16 + lr][ks2 * 32 + lq * 8];
            #pragma unroll
            for (int dt = 0; dt < 4; dt++) {
                bf16x8 bv = *(const bf16x8*)&Vs[dt * 16 + lr][ks2 * 32 + lq * 8];
                o[dt] = __builtin_amdgcn_mfma_f32_16x16x32_bf16(ap, bv, o[dt], 0, 0, 0);
            }
        }
    }

    #pragma unroll
    for (int r = 0; r < 4; r++) {
        float v = l_i[r];
        v += __shfl_xor(v, 1);
        v += __shfl_xor(v, 2);
        v += __shfl_xor(v, 4);
        v += __shfl_xor(v, 8);
        l_i[r] = v;
    }
    __bf16* pob = po + (((size_t)(ck * NHEAD + h) * N_TOK) + qbase) * HD;
    #pragma unroll
    for (int dt = 0; dt < 4; dt++)
        #pragma unroll
        for (int r = 0; r < 4; r++)
            pob[(lq * 4 + r) * HD + dt * 16 + lr] = (__bf16)o[dt][r];
    if (lr == 0) {
        #pragma unroll
        for (int r = 0; r < 4; r++)
            pl[(size_t)(ck * NHEAD + h) * N_TOK + qbase + lq * 4 + r] = l_i[r];
    }
}

// ---------------- combine split-K partials (x4 vectorized), scatter to ctx ----------------
__global__ __launch_bounds__(256) void combine_kernel(const __bf16* __restrict__ po,
                                                      const float* __restrict__ pl,
                                                      const int* __restrict__ perm,
                                                      __bf16* __restrict__ ctx) {
    const int e = blockIdx.x * 256 + threadIdx.x;   // over 4096*128 col4-groups
    const int q = e >> 7;
    const int col = (e & 127) * 4;
    const int h = col >> 6, d = col & 63;
    float s0 = 0.f, s1 = 0.f, s2 = 0.f, s3 = 0.f, l = 0.f;
    #pragma unroll
    for (int c = 0; c < SPLITK; c++) {
        const bf16x4 v = *(const bf16x4*)&po[(((size_t)(c * NHEAD + h) * N_TOK) + q) * HD + d];
        s0 += (float)v[0]; s1 += (float)v[1]; s2 += (float)v[2]; s3 += (float)v[3];
        l += pl[(size_t)(c * NHEAD + h) * N_TOK + q];
    }
    const float rl = 1.0f / l;
    bf16x4 o;
    o[0] = (__bf16)(s0 * rl); o[1] = (__bf16)(s1 * rl);
    o[2] = (__bf16)(s2 * rl); o[3] = (__bf16)(s3 * rl);
    *(bf16x4*)&ctx[(size_t)perm[q] * EDIM + col] = o;
}

// ---------------- fused final GEMM: h = ctx @ weff^T + add2[dmask] + tv[step] ----------------
// 128x64 tiles, grid (32, 8) = 256 blocks; wave = 32 rows x 64 cols, acc[2][4].
__global__ __launch_bounds__(256) void gemm_fused(const __bf16* __restrict__ A,
                                                  const __bf16* __restrict__ B,
                                                  const int* __restrict__ dmask,
                                                  const int* __restrict__ steps,
                                                  const float* __restrict__ add2,
                                                  const float* __restrict__ tv,
                                                  float* __restrict__ C) {
    __shared__ __attribute__((aligned(16))) __bf16 As[128][40];
    __shared__ __attribute__((aligned(16))) __bf16 Bs[64][40];
    const int tid = threadIdx.x;
    const int wave = tid >> 6, lane = tid & 63;
    const int wm = wave * 32;
    const int bm = blockIdx.x * 128, bn = blockIdx.y * 64;
    const int lr = lane & 15, lq = lane >> 4;

    f32x4 acc[2][4] = {};
    for (int k0 = 0; k0 < EDIM; k0 += 32) {
        __syncthreads();
        #pragma unroll
        for (int c = tid; c < 768; c += 256) {
            if (c < 512) {
                const int row = c >> 2, k8 = (c & 3) * 8;
                *(bf16x8*)&As[row][k8] = *(const bf16x8*)&A[(size_t)(bm + row) * EDIM + k0 + k8];
            } else {
                const int c2 = c - 512;
                const int row = c2 >> 2, k8 = (c2 & 3) * 8;
                *(bf16x8*)&Bs[row][k8] = *(const bf16x8*)&B[(size_t)(bn + row) * EDIM + k0 + k8];
            }
        }
        __syncthreads();
        bf16x8 af[2], bfr[4];
        #pragma unroll
        for (int i = 0; i < 2; i++)
            af[i] = *(const bf16x8*)&As[wm + i * 16 + lr][lq * 8];
        #pragma unroll
        for (int j = 0; j < 4; j++)
            bfr[j] = *(const bf16x8*)&Bs[j * 16 + lr][lq * 8];
        #pragma unroll
        for (int i = 0; i < 2; i++)
            #pragma unroll
            for (int j = 0; j < 4; j++)
                acc[i][j] = __builtin_amdgcn_mfma_f32_16x16x32_bf16(af[i], bfr[j], acc[i][j], 0, 0, 0);
    }

    int dmr[2][4], str[2][4];
    #pragma unroll
    for (int i = 0; i < 2; i++)
        #pragma unroll
        for (int r = 0; r < 4; r++) {
            const int row = bm + wm + i * 16 + lq * 4 + r;
            dmr[i][r] = dmask[row];
            str[i][r] = min(max(steps[row], 0), NBIN - 1);
        }
    #pragma unroll
    for (int i = 0; i < 2; i++)
        #pragma unroll
        for (int j = 0; j < 4; j++) {
            const int col = bn + j * 16 + lr;
            #pragma unroll
            for (int r = 0; r < 4; r++) {
                const int row = bm + wm + i * 16 + lq * 4 + r;
                C[(size_t)row * EDIM + col] = acc[i][j][r]
                    + add2[dmr[i][r] * EDIM + col] + tv[str[i][r] * EDIM + col];
            }
        }
}

// ---------------- LayerNorm + ReLU + residual ----------------
__global__ __launch_bounds__(256) void ln_kernel(const float* __restrict__ h,
                                                 const float* __restrict__ x,
                                                 const float* __restrict__ gamma,
                                                 const float* __restrict__ beta,
                                                 float* __restrict__ out) {
    const int row = blockIdx.x * 4 + (threadIdx.x >> 6);
    const int lane = threadIdx.x & 63;
    const float* hr = h + (size_t)row * EDIM;
    float4 v0 = ((const float4*)hr)[lane];
    float4 v1 = ((const float4*)hr)[64 + lane];
    float sum = v0.x + v0.y + v0.z + v0.w + v1.x + v1.y + v1.z + v1.w;
    float sq = v0.x * v0.x + v0.y * v0.y + v0.z * v0.z + v0.w * v0.w +
               v1.x * v1.x + v1.y * v1.y + v1.z * v1.z + v1.w * v1.w;
    #pragma unroll
    for (int m = 1; m < 64; m <<= 1) {
        sum += __shfl_xor(sum, m);
        sq  += __shfl_xor(sq, m);
    }
    const float mean = sum * (1.0f / EDIM);
    const float var = sq * (1.0f / EDIM) - mean * mean;
    const float rstd = rsqrtf(var + 1e-5f);
    const float* xr = x + (size_t)row * EDIM;
    float* orow = out + (size_t)row * EDIM;
    #pragma unroll
    for (int half = 0; half < 2; half++) {
        const float4 v = half ? v1 : v0;
        const int cb = half * 256 + lane * 4;
        const float* vp = (const float*)&v;
        float4 res;
        float tmp[4];
        #pragma unroll
        for (int i = 0; i < 4; i++) {
            const int c = cb + i;
            float t = (vp[i] - mean) * rstd * gamma[c] + beta[c];
            t = fmaxf(t, 0.f);
            tmp[i] = xr[c] + t;
        }
        res.x = tmp[0]; res.y = tmp[1]; res.z = tmp[2]; res.w = tmp[3];
        ((float4*)orow)[cb >> 2] = res;
    }
}

// ---------------- launch ----------------
extern "C" void kernel_launch(void* const* d_in, const int* in_sizes, int n_in,
                              void* d_out, int out_size, void* d_ws, size_t ws_size,
                              hipStream_t stream) {
    const float* x      = (const float*)d_in[0];
    const int*   dmask  = (const int*)d_in[1];
    const int*   steps  = (const int*)d_in[2];
    const float* status = (const float*)d_in[3];
    const float* w_in   = (const float*)d_in[4];
    const float* b_in   = (const float*)d_in[5];
    const float* w_out  = (const float*)d_in[6];
    const float* b_out  = (const float*)d_in[7];
    const float* w_mlp  = (const float*)d_in[8];
    const float* b_mlp  = (const float*)d_in[9];
    const float* gamma  = (const float*)d_in[10];
    const float* beta   = (const float*)d_in[11];
    float* out = (float*)d_out;

    char* ws = (char*)d_ws;
    size_t off = 0;
    auto alloc = [&](size_t bytes) {
        void* ptr = ws + off;
        off = (off + bytes + 255) & ~(size_t)255;
        return ptr;
    };
    __bf16* woutT_bf= (__bf16*)alloc((size_t)EDIM * EDIM * 2);
    __bf16* weff_bf = (__bf16*)alloc((size_t)EDIM * EDIM * 2);
    __bf16* qs_bf   = (__bf16*)alloc((size_t)N_TOK * EDIM * 2);
    __bf16* ks_bf   = (__bf16*)alloc((size_t)N_TOK * EDIM * 2);
    __bf16* vt_bf   = (__bf16*)alloc((size_t)EDIM * N_TOK * 2);
    __bf16* ctx_bf  = (__bf16*)alloc((size_t)N_TOK * EDIM * 2);
    float*  h_f32   = (float*)alloc((size_t)N_TOK * EDIM * 4);
    int*    perm    = (int*)alloc(N_TOK * 4);
    int*    sstep   = (int*)alloc(N_TOK * 4);
    int*    bs_row  = (int*)alloc(N_TOK * 4);
    int*    qinfo   = (int*)alloc(128 * 4);
    __bf16* po      = (__bf16*)alloc((size_t)SPLITK * NHEAD * N_TOK * HD * 2);
    float*  pl      = (float*)alloc((size_t)SPLITK * NHEAD * N_TOK * 4);
    float*  add2    = (float*)alloc(2 * EDIM * 4);
    float*  tv      = (float*)alloc((size_t)NBIN * EDIM * 4);
    __bf16* tmat    = (__bf16*)alloc(128 * 256 * 2);

    // prep: w_out^T + add2 + time-matrix + sort/plan
    prep_kernel<<<NB_PREP, 256, 0, stream>>>(
        w_mlp, w_out, status, b_out, b_mlp, steps,
        woutT_bf, add2, tmat, perm, sstep, bs_row, qinfo);
    // qkv GEMM (fp32 in-staging cvt, direct sorted qs/ks/vt) + weff GEMM + tv GEMM
    gemm2_kernel<<<404, 256, 0, stream>>>(
        x, w_in, b_in, perm, qs_bf, ks_bf, vt_bf,
        w_mlp, woutT_bf, weff_bf, tmat, tv);
    // attention (BQ=64, split-K grid)
    attn_kernel<<<dim3(64, NHEAD, SPLITK), 256, 0, stream>>>(
        qs_bf, ks_bf, vt_bf, bs_row, qinfo, po, pl);
    // combine partials -> ctx (original token order)
    combine_kernel<<<(N_TOK * EDIM) / 1024, 256, 0, stream>>>(po, pl, perm, ctx_bf);
    // h = ctx @ w_eff^T + add2[dmask] + tv[step]  (128x64 tiles, 256 blocks)
    gemm_fused<<<dim3(N_TOK / 128, EDIM / 64), 256, 0, stream>>>(
        ctx_bf, weff_bf, dmask, steps, add2, tv, h_f32);
    // LN + ReLU + residual
    ln_kernel<<<N_TOK / 4, 256, 0, stream>>>(h_f32, x, gamma, beta, out);
}

// Round 13
// 194.914 us; speedup vs baseline: 1.1092x; 1.1092x over previous
//
#include <hip/hip_runtime.h>
#include <hip/hip_bf16.h>
#include <math.h>

typedef __bf16 bf16x8 __attribute__((ext_vector_type(8)));
typedef __bf16 bf16x4 __attribute__((ext_vector_type(4)));
typedef float f32x4 __attribute__((ext_vector_type(4)));

#define N_TOK 4096
#define EDIM 512
#define NHEAD 8
#define HD 64
#define LDCOMB 896
#define NBIN 100
#define SPLITK 8
#define BK 64

// prep block partition
#define NU_CVT 3264
#define NU_TC 64
#define NU_ADD 128
#define NU_TMAT 128
#define NB_PREP (NU_CVT + NU_TC + NU_ADD + NU_TMAT + 1)

// ---------------- prep: cvt + w_out^T + add2 + time-matrix + sort/plan ----------------
__global__ __launch_bounds__(256) void prep_kernel(
    const float* __restrict__ x, const float* __restrict__ w_in,
    const float* __restrict__ w_mlp, const float* __restrict__ w_out,
    const float* __restrict__ status, const float* __restrict__ out_b,
    const float* __restrict__ mlp_b, const int* __restrict__ steps,
    __bf16* __restrict__ x_bf, __bf16* __restrict__ wqkv_bf,
    __bf16* __restrict__ wmlp_bf, __bf16* __restrict__ woutT_bf,
    float* __restrict__ add2, __bf16* __restrict__ tmat,
    int* __restrict__ perm, int* __restrict__ sstep,
    int* __restrict__ bs_row, int* __restrict__ qinfo) {
    __shared__ float T[64][65];
    __shared__ int hist[NBIN];
    __shared__ int offs[NBIN];
    const int bid = blockIdx.x;
    const int tid = threadIdx.x;
    const int wave = tid >> 6, lane = tid & 63;

    if (bid < NU_CVT) {
        // fp32 -> bf16: x, w_in, w_mlp
        int i = bid * 256 + tid;
        const int n0 = N_TOK * EDIM / 4;
        const int n1 = 3 * EDIM * EDIM / 4;
        const float* src; __bf16* dst;
        if (i < n0)           { src = x; dst = x_bf; }
        else if (i < n0 + n1) { i -= n0; src = w_in; dst = wqkv_bf; }
        else                  { i -= n0 + n1; src = w_mlp; dst = wmlp_bf; }
        const float4 v = ((const float4*)src)[i];
        bf16x4 o;
        o[0] = (__bf16)v.x; o[1] = (__bf16)v.y; o[2] = (__bf16)v.z; o[3] = (__bf16)v.w;
        ((bf16x4*)dst)[i] = o;
    } else if (bid < NU_CVT + NU_TC) {
        // transpose+cvt w_out -> woutT[k][m]
        const int b2 = bid - NU_CVT;
        const int m0 = (b2 >> 3) * 64, k0 = (b2 & 7) * 64;
        const int row = tid >> 2, c4 = (tid & 3) * 16;
        #pragma unroll
        for (int i = 0; i < 4; i++) {
            const float4 v = *(const float4*)&w_out[(size_t)(m0 + row) * EDIM + k0 + c4 + i * 4];
            T[row][c4 + i * 4 + 0] = v.x;
            T[row][c4 + i * 4 + 1] = v.y;
            T[row][c4 + i * 4 + 2] = v.z;
            T[row][c4 + i * 4 + 3] = v.w;
        }
        __syncthreads();
        const int kr = tid >> 2, m16 = (tid & 3) * 16;
        bf16x8 o0, o1;
        #pragma unroll
        for (int i = 0; i < 8; i++) o0[i] = (__bf16)T[m16 + i][kr];
        #pragma unroll
        for (int i = 0; i < 8; i++) o1[i] = (__bf16)T[m16 + 8 + i][kr];
        *(bf16x8*)&woutT_bf[(size_t)(k0 + kr) * EDIM + m0 + m16] = o0;
        *(bf16x8*)&woutT_bf[(size_t)(k0 + kr) * EDIM + m0 + m16 + 8] = o1;
    } else if (bid < NU_CVT + NU_TC + NU_ADD) {
        // add2[m][j] = status[m].w_mlp[j,512:640] + mlp_b[j] + w_mlp[j,:512].b_out
        const int j = (bid - NU_CVT - NU_TC) * 4 + wave;
        const float* wr = w_mlp + (size_t)j * LDCOMB;
        const int k8 = lane * 8;
        const float4 wa = *(const float4*)&wr[k8], wb = *(const float4*)&wr[k8 + 4];
        const float4 oa = *(const float4*)&out_b[k8], ob = *(const float4*)&out_b[k8 + 4];
        float b = wa.x * oa.x + wa.y * oa.y + wa.z * oa.z + wa.w * oa.w +
                  wb.x * ob.x + wb.y * ob.y + wb.z * ob.z + wb.w * ob.w;
        const int c2 = lane * 2;
        const float w0 = wr[EDIM + c2], w1 = wr[EDIM + c2 + 1];
        float s0 = status[c2] * w0 + status[c2 + 1] * w1;
        float s1 = status[128 + c2] * w0 + status[129 + c2] * w1;
        #pragma unroll
        for (int m = 1; m < 64; m <<= 1) {
            b += __shfl_xor(b, m);
            s0 += __shfl_xor(s0, m);
            s1 += __shfl_xor(s1, m);
        }
        if (lane == 0) {
            const float bb = b + mlp_b[j];
            add2[j] = s0 + bb;
            add2[EDIM + j] = s1 + bb;
        }
    } else if (bid < NU_CVT + NU_TC + NU_ADD + NU_TMAT) {
        // bf16 time matrix [128][256] (rows >= 100 are padding, masked at tv store)
        const int st = bid - NU_CVT - NU_TC - NU_ADD;
        const int c = tid;
        const int pp = c >> 1;
        const float div = expf((float)(2 * pp) * (-9.210340371976184f / 256.0f));
        const float ang = (float)st * div;
        tmat[st * 256 + c] = (__bf16)((c & 1) ? cosf(ang) : sinf(ang));
    } else {
        // counting sort by step + bs_row + per-qtile plan
        if (tid < NBIN) hist[tid] = 0;
        __syncthreads();
        for (int i = tid; i < N_TOK; i += 256)
            atomicAdd(&hist[min(max(steps[i], 0), NBIN - 1)], 1);
        __syncthreads();
        if (tid == 0) {
            int acc = 0;
            for (int s = 0; s < NBIN; s++) { offs[s] = acc; acc += hist[s]; }
        }
        __syncthreads();
        if (tid < NBIN) hist[tid] = offs[tid];   // immutable copy of bin_start
        __syncthreads();
        for (int i = tid; i < N_TOK; i += 256) {
            const int s = min(max(steps[i], 0), NBIN - 1);
            const int pos = atomicAdd(&offs[s], 1);
            perm[pos] = i;
            sstep[pos] = s;
        }
        __syncthreads();
        for (int q = tid; q < N_TOK; q += 256)
            bs_row[q] = hist[sstep[q]];
        __syncthreads();
        for (int qt = tid; qt < 64; qt += 256) {
            qinfo[qt * 2] = bs_row[qt * 64] & ~(BK - 1);
            qinfo[qt * 2 + 1] = bs_row[qt * 64 + 63];
        }
    }
}

// ---------------- merged GEMMs: qkv->sorted qs/ks/vt (384) + weff (16) + tv (4) ----------------
__global__ __launch_bounds__(256) void gemm2_kernel(const __bf16* __restrict__ x_bf,
                                                    const __bf16* __restrict__ wqkv_bf,
                                                    const float* __restrict__ b_in,
                                                    const int* __restrict__ perm,
                                                    __bf16* __restrict__ qs,
                                                    __bf16* __restrict__ ks,
                                                    __bf16* __restrict__ vt,
                                                    const __bf16* __restrict__ wmlp_bf,
                                                    const __bf16* __restrict__ woutT_bf,
                                                    __bf16* __restrict__ weff_bf,
                                                    const __bf16* __restrict__ tmat,
                                                    float* __restrict__ tv) {
    __shared__ __attribute__((aligned(16))) union {
        struct { __bf16 As[128][40]; __bf16 Bs[128][40]; } g;
        __bf16 T[128][72];
    } sm;
    __shared__ int pr[128];
    const int bid = blockIdx.x;
    const int tid = threadIdx.x;
    const int wave = tid >> 6, lane = tid & 63;
    const int wm = (wave >> 1) * 64, wn = (wave & 1) * 64;
    const int lr = lane & 15, lq = lane >> 4;

    const __bf16 *A, *B;
    int lda, ldb, bm, bn, K, mode;
    if (bid < 384) {
        A = x_bf; lda = EDIM; B = wqkv_bf; ldb = EDIM; K = EDIM; mode = 0;
        bm = (bid & 31) * 128; bn = (bid >> 5) * 128;
        if (tid < 128) pr[tid] = perm[bm + tid];
    } else if (bid < 400) {
        const int b2 = bid - 384;
        A = wmlp_bf; lda = LDCOMB; B = woutT_bf; ldb = EDIM; K = EDIM; mode = 1;
        bm = (b2 & 3) * 128; bn = (b2 >> 2) * 128;
    } else {
        const int b3 = bid - 400;
        A = tmat; lda = 256; B = wmlp_bf + 640; ldb = LDCOMB; K = 256; mode = 2;
        bm = 0; bn = b3 * 128;
    }

    f32x4 acc[4][4] = {};
    for (int k0 = 0; k0 < K; k0 += 32) {
        __syncthreads();
        #pragma unroll
        for (int c = tid; c < 512; c += 256) {
            const int row = c >> 2, k8 = (c & 3) * 8;
            const int arow = (mode == 0) ? pr[row] : (bm + row);
            *(bf16x8*)&sm.g.As[row][k8] = *(const bf16x8*)&A[(size_t)arow * lda + k0 + k8];
            *(bf16x8*)&sm.g.Bs[row][k8] = *(const bf16x8*)&B[(size_t)(bn + row) * ldb + k0 + k8];
        }
        __syncthreads();
        bf16x8 af[4], bfr[4];
        #pragma unroll
        for (int i = 0; i < 4; i++) {
            af[i]  = *(const bf16x8*)&sm.g.As[wm + i * 16 + lr][lq * 8];
            bfr[i] = *(const bf16x8*)&sm.g.Bs[wn + i * 16 + lr][lq * 8];
        }
        #pragma unroll
        for (int i = 0; i < 4; i++)
            #pragma unroll
            for (int j = 0; j < 4; j++)
                acc[i][j] = __builtin_amdgcn_mfma_f32_16x16x32_bf16(af[i], bfr[j], acc[i][j], 0, 0, 0);
    }

    if (mode == 1) {
        #pragma unroll
        for (int i = 0; i < 4; i++)
            #pragma unroll
            for (int j = 0; j < 4; j++) {
                const int col = bn + wn + j * 16 + lr;
                #pragma unroll
                for (int r = 0; r < 4; r++)
                    weff_bf[(size_t)(bm + wm + i * 16 + lq * 4 + r) * EDIM + col] =
                        (__bf16)acc[i][j][r];
            }
    } else if (mode == 2) {
        #pragma unroll
        for (int i = 0; i < 4; i++)
            #pragma unroll
            for (int j = 0; j < 4; j++) {
                const int col = bn + wn + j * 16 + lr;
                #pragma unroll
                for (int r = 0; r < 4; r++) {
                    const int row = wm + i * 16 + lq * 4 + r;
                    if (row < NBIN) tv[(size_t)row * EDIM + col] = acc[i][j][r];
                }
            }
    } else if (bn < 512) {
        // Q: pre-scale by 1/8*log2(e), sorted rows
        const float SC = 0.125f * 1.44269504f;
        #pragma unroll
        for (int i = 0; i < 4; i++)
            #pragma unroll
            for (int j = 0; j < 4; j++) {
                const int col = bn + wn + j * 16 + lr;
                const float bv = b_in[col];
                #pragma unroll
                for (int r = 0; r < 4; r++)
                    qs[(size_t)(bm + wm + i * 16 + lq * 4 + r) * EDIM + col] =
                        (__bf16)((acc[i][j][r] + bv) * SC);
            }
    } else if (bn < 1024) {
        // K: sorted rows
        #pragma unroll
        for (int i = 0; i < 4; i++)
            #pragma unroll
            for (int j = 0; j < 4; j++) {
                const int col = bn + wn + j * 16 + lr;
                const float bv = b_in[col];
                #pragma unroll
                for (int r = 0; r < 4; r++)
                    ks[(size_t)(bm + wm + i * 16 + lq * 4 + r) * EDIM + (col - 512)] =
                        (__bf16)(acc[i][j][r] + bv);
            }
    } else {
        // V: transpose 128x128 tile via LDS, two 64-col halves -> vt[dim][token]
        #pragma unroll
        for (int half = 0; half < 2; half++) {
            __syncthreads();
            if ((wave & 1) == half) {
                #pragma unroll
                for (int i = 0; i < 4; i++)
                    #pragma unroll
                    for (int j = 0; j < 4; j++) {
                        const float bv = b_in[bn + wn + j * 16 + lr];
                        #pragma unroll
                        for (int r = 0; r < 4; r++)
                            sm.T[wm + i * 16 + lq * 4 + r][j * 16 + lr] =
                                (__bf16)(acc[i][j][r] + bv);
                    }
            }
            __syncthreads();
            for (int u = tid; u < 1024; u += 256) {
                const int d = u & 63, t8 = (u >> 6) * 8;
                bf16x8 v;
                #pragma unroll
                for (int j = 0; j < 8; j++) v[j] = sm.T[t8 + j][d];
                const int dim = (bn - 1024) + half * 64 + d;
                *(bf16x8*)&vt[(size_t)dim * N_TOK + bm + t8] = v;
            }
        }
    }
}

// ---------------- flash attention: BQ=64, split-K grid, XCD-swizzled h, MFMA row-sum ----------------
__global__ __launch_bounds__(256) void attn_kernel(const __bf16* __restrict__ qs,
                                                   const __bf16* __restrict__ ks,
                                                   const __bf16* __restrict__ vt,
                                                   const int* __restrict__ bs_row,
                                                   const int* __restrict__ qinfo,
                                                   __bf16* __restrict__ po,
                                                   float* __restrict__ pl) {
    __shared__ __attribute__((aligned(16))) __bf16 Ks[BK][72];     // [key][d]
    __shared__ __attribute__((aligned(16))) __bf16 Vs[64][BK + 8]; // [d][key]
    __shared__ __attribute__((aligned(16))) __bf16 Ps[64][BK + 8]; // [q][key] wave bands

    // XCD-aware swizzle: h = blockIdx.x & 7 so same-XCD residents share one head's K/V
    const int h = blockIdx.x & 7;
    const int qtile = (blockIdx.x >> 3) | (blockIdx.y << 3);
    const int ck = blockIdx.z;
    const int tid = threadIdx.x, wave = tid >> 6, lane = tid & 63;
    const int lr = lane & 15, lq = lane >> 4;
    const int qbase = qtile * 64 + wave * 16;

    const int kt0 = qinfo[qtile * 2];
    const int bs_blockmax = qinfo[qtile * 2 + 1];
    const int nt = (N_TOK - kt0) / BK;
    const int kta = kt0 + ((nt * ck) / SPLITK) * BK;
    const int ktb = kt0 + ((nt * (ck + 1)) / SPLITK) * BK;

    bf16x8 aq[2];
    {
        const __bf16* qrow = qs + (size_t)(qbase + lr) * EDIM + h * HD;
        aq[0] = *(const bf16x8*)&qrow[lq * 8];
        aq[1] = *(const bf16x8*)&qrow[32 + lq * 8];
    }
    int bs_r[4];
    #pragma unroll
    for (int r = 0; r < 4; r++) bs_r[r] = bs_row[qbase + lq * 4 + r];

    bf16x8 ones;
    #pragma unroll
    for (int i = 0; i < 8; i++) ones[i] = (__bf16)1.0f;

    f32x4 lacc = {};   // row-sums of P via ones-MFMA (denominator)
    f32x4 o[4] = {};

    const __bf16* kbase = ks + h * HD;
    const __bf16* vbase = vt + (size_t)h * HD * N_TOK;

    const int r0 = tid >> 3, r1 = r0 + 32, k8 = (tid & 7) * 8;
    bf16x8 kr0, kr1, vr0, vr1;
    if (kta < ktb) {
        kr0 = *(const bf16x8*)&kbase[(size_t)(kta + r0) * EDIM + k8];
        kr1 = *(const bf16x8*)&kbase[(size_t)(kta + r1) * EDIM + k8];
        vr0 = *(const bf16x8*)&vbase[(size_t)r0 * N_TOK + kta + k8];
        vr1 = *(const bf16x8*)&vbase[(size_t)r1 * N_TOK + kta + k8];
    }

    for (int kt = kta; kt < ktb; kt += BK) {
        __syncthreads();
        *(bf16x8*)&Ks[r0][k8] = kr0;
        *(bf16x8*)&Ks[r1][k8] = kr1;
        *(bf16x8*)&Vs[r0][k8] = vr0;
        *(bf16x8*)&Vs[r1][k8] = vr1;
        __syncthreads();
        if (kt + BK < ktb) {
            kr0 = *(const bf16x8*)&kbase[(size_t)(kt + BK + r0) * EDIM + k8];
            kr1 = *(const bf16x8*)&kbase[(size_t)(kt + BK + r1) * EDIM + k8];
            vr0 = *(const bf16x8*)&vbase[(size_t)r0 * N_TOK + kt + BK + k8];
            vr1 = *(const bf16x8*)&vbase[(size_t)r1 * N_TOK + kt + BK + k8];
        }

        f32x4 s[4];
        #pragma unroll
        for (int t = 0; t < 4; t++) {
            bf16x8 b0 = *(const bf16x8*)&Ks[t * 16 + lr][lq * 8];
            bf16x8 b1 = *(const bf16x8*)&Ks[t * 16 + lr][32 + lq * 8];
            f32x4 a = {};
            a = __builtin_amdgcn_mfma_f32_16x16x32_bf16(aq[0], b0, a, 0, 0, 0);
            a = __builtin_amdgcn_mfma_f32_16x16x32_bf16(aq[1], b1, a, 0, 0, 0);
            s[t] = a;
        }
        if (kt < bs_blockmax) {
            #pragma unroll
            for (int t = 0; t < 4; t++) {
                const int col = kt + t * 16 + lr;
                #pragma unroll
                for (int r = 0; r < 4; r++)
                    if (col < bs_r[r]) s[t][r] = -1e9f;
            }
        }
        #pragma unroll
        for (int t = 0; t < 4; t++) {
            #pragma unroll
            for (int r = 0; r < 4; r++) {
                const float pr = exp2f(s[t][r]);
                Ps[wave * 16 + lq * 4 + r][t * 16 + lr] = (__bf16)pr;
            }
        }
        #pragma unroll
        for (int ks2 = 0; ks2 < 2; ks2++) {
            bf16x8 ap = *(const bf16x8*)&Ps[wave * 16 + lr][ks2 * 32 + lq * 8];
            lacc = __builtin_amdgcn_mfma_f32_16x16x32_bf16(ap, ones, lacc, 0, 0, 0);
            #pragma unroll
            for (int dt = 0; dt < 4; dt++) {
                bf16x8 bv = *(const bf16x8*)&Vs[dt * 16 + lr][ks2 * 32 + lq * 8];
                o[dt] = __builtin_amdgcn_mfma_f32_16x16x32_bf16(ap, bv, o[dt], 0, 0, 0);
            }
        }
    }

    // lacc[r] = full row sum for q-row lq*4+r (all 16 cols identical; no shuffle needed)
    __bf16* pob = po + (((size_t)(ck * NHEAD + h) * N_TOK) + qbase) * HD;
    #pragma unroll
    for (int dt = 0; dt < 4; dt++)
        #pragma unroll
        for (int r = 0; r < 4; r++)
            pob[(lq * 4 + r) * HD + dt * 16 + lr] = (__bf16)o[dt][r];
    if (lr == 0) {
        #pragma unroll
        for (int r = 0; r < 4; r++)
            pl[(size_t)(ck * NHEAD + h) * N_TOK + qbase + lq * 4 + r] = lacc[r];
    }
}

// ---------------- combine split-K partials (x4 vectorized), scatter to ctx ----------------
__global__ __launch_bounds__(256) void combine_kernel(const __bf16* __restrict__ po,
                                                      const float* __restrict__ pl,
                                                      const int* __restrict__ perm,
                                                      __bf16* __restrict__ ctx) {
    const int e = blockIdx.x * 256 + threadIdx.x;   // over 4096*128 col4-groups
    const int q = e >> 7;
    const int col = (e & 127) * 4;
    const int h = col >> 6, d = col & 63;
    float s0 = 0.f, s1 = 0.f, s2 = 0.f, s3 = 0.f, l = 0.f;
    #pragma unroll
    for (int c = 0; c < SPLITK; c++) {
        const bf16x4 v = *(const bf16x4*)&po[(((size_t)(c * NHEAD + h) * N_TOK) + q) * HD + d];
        s0 += (float)v[0]; s1 += (float)v[1]; s2 += (float)v[2]; s3 += (float)v[3];
        l += pl[(size_t)(c * NHEAD + h) * N_TOK + q];
    }
    const float rl = 1.0f / l;
    bf16x4 o;
    o[0] = (__bf16)(s0 * rl); o[1] = (__bf16)(s1 * rl);
    o[2] = (__bf16)(s2 * rl); o[3] = (__bf16)(s3 * rl);
    *(bf16x4*)&ctx[(size_t)perm[q] * EDIM + col] = o;
}

// ---------------- fused final GEMM: h = ctx @ weff^T + add2[dmask] + tv[step] ----------------
__global__ __launch_bounds__(256) void gemm_fused(const __bf16* __restrict__ A,
                                                  const __bf16* __restrict__ B,
                                                  const int* __restrict__ dmask,
                                                  const int* __restrict__ steps,
                                                  const float* __restrict__ add2,
                                                  const float* __restrict__ tv,
                                                  float* __restrict__ C) {
    __shared__ __attribute__((aligned(16))) __bf16 As[128][40];
    __shared__ __attribute__((aligned(16))) __bf16 Bs[128][40];
    const int tid = threadIdx.x;
    const int wave = tid >> 6, lane = tid & 63;
    const int wm = (wave >> 1) * 64, wn = (wave & 1) * 64;
    const int bm = blockIdx.x * 128, bn = blockIdx.y * 128;
    const int lr = lane & 15, lq = lane >> 4;

    f32x4 acc[4][4] = {};
    for (int k0 = 0; k0 < EDIM; k0 += 32) {
        __syncthreads();
        #pragma unroll
        for (int c = tid; c < 512; c += 256) {
            const int row = c >> 2, k8 = (c & 3) * 8;
            *(bf16x8*)&As[row][k8] = *(const bf16x8*)&A[(size_t)(bm + row) * EDIM + k0 + k8];
            *(bf16x8*)&Bs[row][k8] = *(const bf16x8*)&B[(size_t)(bn + row) * EDIM + k0 + k8];
        }
        __syncthreads();
        bf16x8 af[4], bfr[4];
        #pragma unroll
        for (int i = 0; i < 4; i++) {
            af[i]  = *(const bf16x8*)&As[wm + i * 16 + lr][lq * 8];
            bfr[i] = *(const bf16x8*)&Bs[wn + i * 16 + lr][lq * 8];
        }
        #pragma unroll
        for (int i = 0; i < 4; i++)
            #pragma unroll
            for (int j = 0; j < 4; j++)
                acc[i][j] = __builtin_amdgcn_mfma_f32_16x16x32_bf16(af[i], bfr[j], acc[i][j], 0, 0, 0);
    }

    int dmr[4][4], str[4][4];
    #pragma unroll
    for (int i = 0; i < 4; i++)
        #pragma unroll
        for (int r = 0; r < 4; r++) {
            const int row = bm + wm + i * 16 + lq * 4 + r;
            dmr[i][r] = dmask[row];
            str[i][r] = min(max(steps[row], 0), NBIN - 1);
        }
    #pragma unroll
    for (int i = 0; i < 4; i++)
        #pragma unroll
        for (int j = 0; j < 4; j++) {
            const int col = bn + wn + j * 16 + lr;
            #pragma unroll
            for (int r = 0; r < 4; r++) {
                const int row = bm + wm + i * 16 + lq * 4 + r;
                C[(size_t)row * EDIM + col] = acc[i][j][r]
                    + add2[dmr[i][r] * EDIM + col] + tv[str[i][r] * EDIM + col];
            }
        }
}

// ---------------- LayerNorm + ReLU + residual ----------------
__global__ __launch_bounds__(256) void ln_kernel(const float* __restrict__ h,
                                                 const float* __restrict__ x,
                                                 const float* __restrict__ gamma,
                                                 const float* __restrict__ beta,
                                                 float* __restrict__ out) {
    const int row = blockIdx.x * 4 + (threadIdx.x >> 6);
    const int lane = threadIdx.x & 63;
    const float* hr = h + (size_t)row * EDIM;
    float4 v0 = ((const float4*)hr)[lane];
    float4 v1 = ((const float4*)hr)[64 + lane];
    float sum = v0.x + v0.y + v0.z + v0.w + v1.x + v1.y + v1.z + v1.w;
    float sq = v0.x * v0.x + v0.y * v0.y + v0.z * v0.z + v0.w * v0.w +
               v1.x * v1.x + v1.y * v1.y + v1.z * v1.z + v1.w * v1.w;
    #pragma unroll
    for (int m = 1; m < 64; m <<= 1) {
        sum += __shfl_xor(sum, m);
        sq  += __shfl_xor(sq, m);
    }
    const float mean = sum * (1.0f / EDIM);
    const float var = sq * (1.0f / EDIM) - mean * mean;
    const float rstd = rsqrtf(var + 1e-5f);
    const float* xr = x + (size_t)row * EDIM;
    float* orow = out + (size_t)row * EDIM;
    #pragma unroll
    for (int half = 0; half < 2; half++) {
        const float4 v = half ? v1 : v0;
        const int cb = half * 256 + lane * 4;
        const float* vp = (const float*)&v;
        float4 res;
        float tmp[4];
        #pragma unroll
        for (int i = 0; i < 4; i++) {
            const int c = cb + i;
            float t = (vp[i] - mean) * rstd * gamma[c] + beta[c];
            t = fmaxf(t, 0.f);
            tmp[i] = xr[c] + t;
        }
        res.x = tmp[0]; res.y = tmp[1]; res.z = tmp[2]; res.w = tmp[3];
        ((float4*)orow)[cb >> 2] = res;
    }
}

// ---------------- launch ----------------
extern "C" void kernel_launch(void* const* d_in, const int* in_sizes, int n_in,
                              void* d_out, int out_size, void* d_ws, size_t ws_size,
                              hipStream_t stream) {
    const float* x      = (const float*)d_in[0];
    const int*   dmask  = (const int*)d_in[1];
    const int*   steps  = (const int*)d_in[2];
    const float* status = (const float*)d_in[3];
    const float* w_in   = (const float*)d_in[4];
    const float* b_in   = (const float*)d_in[5];
    const float* w_out  = (const float*)d_in[6];
    const float* b_out  = (const float*)d_in[7];
    const float* w_mlp  = (const float*)d_in[8];
    const float* b_mlp  = (const float*)d_in[9];
    const float* gamma  = (const float*)d_in[10];
    const float* beta   = (const float*)d_in[11];
    float* out = (float*)d_out;

    char* ws = (char*)d_ws;
    size_t off = 0;
    auto alloc = [&](size_t bytes) {
        void* ptr = ws + off;
        off = (off + bytes + 255) & ~(size_t)255;
        return ptr;
    };
    __bf16* x_bf    = (__bf16*)alloc((size_t)N_TOK * EDIM * 2);
    __bf16* wqkv_bf = (__bf16*)alloc((size_t)3 * EDIM * EDIM * 2);
    __bf16* wmlp_bf = (__bf16*)alloc((size_t)EDIM * LDCOMB * 2);
    __bf16* woutT_bf= (__bf16*)alloc((size_t)EDIM * EDIM * 2);
    __bf16* weff_bf = (__bf16*)alloc((size_t)EDIM * EDIM * 2);
    __bf16* qs_bf   = (__bf16*)alloc((size_t)N_TOK * EDIM * 2);
    __bf16* ks_bf   = (__bf16*)alloc((size_t)N_TOK * EDIM * 2);
    __bf16* vt_bf   = (__bf16*)alloc((size_t)EDIM * N_TOK * 2);
    __bf16* ctx_bf  = (__bf16*)alloc((size_t)N_TOK * EDIM * 2);
    float*  h_f32   = (float*)alloc((size_t)N_TOK * EDIM * 4);
    int*    perm    = (int*)alloc(N_TOK * 4);
    int*    sstep   = (int*)alloc(N_TOK * 4);
    int*    bs_row  = (int*)alloc(N_TOK * 4);
    int*    qinfo   = (int*)alloc(128 * 4);
    __bf16* po      = (__bf16*)alloc((size_t)SPLITK * NHEAD * N_TOK * HD * 2);
    float*  pl      = (float*)alloc((size_t)SPLITK * NHEAD * N_TOK * 4);
    float*  add2    = (float*)alloc(2 * EDIM * 4);
    float*  tv      = (float*)alloc((size_t)NBIN * EDIM * 4);
    __bf16* tmat    = (__bf16*)alloc(128 * 256 * 2);

    // prep: converts + w_out^T + add2 + time-matrix + sort/plan
    prep_kernel<<<NB_PREP, 256, 0, stream>>>(
        x, w_in, w_mlp, w_out, status, b_out, b_mlp, steps,
        x_bf, wqkv_bf, wmlp_bf, woutT_bf, add2, tmat, perm, sstep, bs_row, qinfo);
    // qkv GEMM (direct sorted qs/ks/vt) + weff GEMM + tv GEMM
    gemm2_kernel<<<404, 256, 0, stream>>>(
        x_bf, wqkv_bf, b_in, perm, qs_bf, ks_bf, vt_bf,
        wmlp_bf, woutT_bf, weff_bf, tmat, tv);
    // attention (BQ=64, split-K grid, XCD-swizzled h, MFMA row-sum)
    attn_kernel<<<dim3(64, NHEAD, SPLITK), 256, 0, stream>>>(
        qs_bf, ks_bf, vt_bf, bs_row, qinfo, po, pl);
    // combine partials -> ctx (original token order)
    combine_kernel<<<(N_TOK * EDIM) / 1024, 256, 0, stream>>>(po, pl, perm, ctx_bf);
    // h = ctx @ w_eff^T + add2[dmask] + tv[step]
    gemm_fused<<<dim3(N_TOK / 128, EDIM / 128), 256, 0, stream>>>(
        ctx_bf, weff_bf, dmask, steps, add2, tv, h_f32);
    // LN + ReLU + residual
    ln_kernel<<<N_TOK / 4, 256, 0, stream>>>(h_f32, x, gamma, beta, out);
}